// Round 10
// baseline (103.881 us; speedup 1.0000x reference)
//
#include <hip/hip_runtime.h>

#define B_ 2
#define S_ 8192
#define H_ 8
#define D_ 64
#define HD_ 512
#define WIN_ 512

typedef __bf16 bf16x8 __attribute__((ext_vector_type(8)));
typedef float f32x4 __attribute__((ext_vector_type(4)));
typedef unsigned short u16;
typedef unsigned int u32;

__device__ __forceinline__ u16 f2bf(float f) {
  u32 u = __float_as_uint(f);
  u += 0x7FFFu + ((u >> 16) & 1u);
  return (u16)(u >> 16);
}

__device__ __forceinline__ bf16x8 cvt8s(const float* p, float s) {
  const float4 a = *(const float4*)p;
  const float4 b = *(const float4*)(p + 4);
  union { u16 s[8]; bf16x8 v; } r;
  r.s[0] = f2bf(a.x * s); r.s[1] = f2bf(a.y * s); r.s[2] = f2bf(a.z * s); r.s[3] = f2bf(a.w * s);
  r.s[4] = f2bf(b.x * s); r.s[5] = f2bf(b.y * s); r.s[6] = f2bf(b.z * s); r.s[7] = f2bf(b.w * s);
  return r.v;
}

#define MFMA(a, b, c) __builtin_amdgcn_mfma_f32_16x16x32_bf16(a, b, c, 0, 0, 0)

// ---------------------------------------------------------------------------
// V [B,S,H,D] fp32 -> Vt [B,H,D,S] bf16  (LDS-tiled transpose, 64x64 tiles)
// ---------------------------------------------------------------------------
__global__ __launch_bounds__(256) void vtrans_kernel(const float* __restrict__ v,
                                                     u16* __restrict__ vt) {
  const int t = threadIdx.x;
  const int s0 = (blockIdx.x & (S_ / 64 - 1)) * 64;
  const int bh = blockIdx.x >> 7;  // S_/64 = 128
  const int b = bh >> 3, h = bh & 7;
  __shared__ float tile[64][65];
#pragma unroll
  for (int it = 0; it < 16; ++it) {
    int idx = it * 256 + t;
    int r = idx >> 6, c = idx & 63;
    tile[r][c] = v[((size_t)(b * S_ + s0 + r) * H_ + h) * D_ + c];
  }
  __syncthreads();
#pragma unroll
  for (int it = 0; it < 16; ++it) {
    int idx = it * 256 + t;
    int dd = idx >> 6, c = idx & 63;
    vt[((size_t)(b * H_ + h) * D_ + dd) * S_ + s0 + c] = f2bf(tile[c][dd]);
  }
}

// ---------------------------------------------------------------------------
// generic fp32 -> bf16 conversion (vectorized x4)
// ---------------------------------------------------------------------------
__global__ __launch_bounds__(256) void cvt_kernel(const float* __restrict__ in,
                                                  u16* __restrict__ out, int n4) {
  int i = blockIdx.x * 256 + threadIdx.x;
  if (i < n4) {
    float4 f = ((const float4*)in)[i];
    ushort4 r;
    r.x = f2bf(f.x); r.y = f2bf(f.y); r.z = f2bf(f.z); r.w = f2bf(f.w);
    ((ushort4*)out)[i] = r;
  }
}

// ---------------------------------------------------------------------------
// Block-cooperative sliding-window flash attention.
// 256 threads = 4 waves x 32 queries (2 fragment-sets). Block owns 128 q.
// K [32k][72 elem] / V^T [64d][40] / P [16q][40] LDS tiles with ODD row
// strides (bank-balanced, no XOR). Double-buffered staging, 1 barrier/tile.
// Fixed-reference exp2 softmax; truncating P->bf16 (1 VALU).
// ---------------------------------------------------------------------------
__global__ __launch_bounds__(256) void attn_kernel(const float* __restrict__ q,
                                                   const u16* __restrict__ kb,
                                                   const u16* __restrict__ vt,
                                                   u16* __restrict__ attn) {
  const int tid = threadIdx.x;
  const int lane = tid & 63;
  const int wave = tid >> 6;   // 0..3
  const int lg = lane >> 4;    // 0..3
  const int lj = lane & 15;    // 0..15
  // XCD swizzle: 1024 blocks, 8 XCDs, 128-block contiguous chunks (bijective)
  const int bid = (int)blockIdx.x;
  const int swz = (bid & 7) * 128 + (bid >> 3);
  const int qc = swz & 63;     // S_/128 = 64 query chunks
  const int bh = swz >> 6;
  const int b = bh >> 3, h = bh & 7;
  const int q0blk = qc * 128;
  const int q0w = q0blk + wave * 32;

  __shared__ __align__(16) u16 klds[2][32 * 72];      // 4608B x2
  __shared__ __align__(16) u16 vlds[2][64 * 40];      // 5120B x2
  __shared__ __align__(16) u16 plds[4][2][16 * 40];   // 1280B x8

  // Q fragments pre-scaled by 1/sqrt(D)*log2(e): exp2(mfma) == softmax exp
  const float qscale = 0.125f * 1.4426950408889634f;
  bf16x8 aq[2][2];
#pragma unroll
  for (int qs = 0; qs < 2; ++qs) {
    const float* qrow = q + ((size_t)(b * S_ + q0w + qs * 16 + lj) * H_ + h) * D_;
    aq[qs][0] = cvt8s(qrow + lg * 8, qscale);
    aq[qs][1] = cvt8s(qrow + 32 + lg * 8, qscale);
  }

  f32x4 o[2][4];
#pragma unroll
  for (int qs = 0; qs < 2; ++qs)
#pragma unroll
    for (int g = 0; g < 4; ++g) o[qs][g] = (f32x4){0.f, 0.f, 0.f, 0.f};
  float lacc[2][4] = {};

  // per-qset tile ranges (absolute key-tile = key/32)
  int tbq[2], teq[2];
  bool wm[2];
#pragma unroll
  for (int qs = 0; qs < 2; ++qs) {
    const int qq = q0w + qs * 16;
    wm[qs] = (qq >= WIN_);
    tbq[qs] = wm[qs] ? ((qq - (WIN_ - 1)) >> 5) : 0;
    teq[qs] = (qq + 15) >> 5;
  }
  const int tbu = (q0blk >= WIN_) ? ((q0blk - (WIN_ - 1)) >> 5) : 0;
  const int teu = (q0blk + 127) >> 5;

  // ---- staging: threads 0-127 stage K (2x16B), 128-255 stage V^T ----
  const u16 *g0, *g1;
  size_t gstep;
  int dst0, dst1;
  bool stK = (tid < 128);
  if (stK) {
    const int ch0 = tid, ch1 = tid + 128;       // 256 chunks: r=ch>>3, c=ch&7
    const int r0 = ch0 >> 3, c0 = ch0 & 7;
    const int r1 = ch1 >> 3, c1 = ch1 & 7;
    g0 = kb + ((size_t)(b * S_ + r0) * H_ + h) * D_ + c0 * 8;
    g1 = kb + ((size_t)(b * S_ + r1) * H_ + h) * D_ + c1 * 8;
    gstep = (size_t)32 * HD_;
    dst0 = r0 * 72 + c0 * 8;
    dst1 = r1 * 72 + c1 * 8;
  } else {
    const int u = tid - 128;
    const int ch0 = u, ch1 = u + 128;           // 256 chunks: d=ch>>2, c=ch&3
    const int d0 = ch0 >> 2, c0 = ch0 & 3;
    const int d1 = ch1 >> 2, c1 = ch1 & 3;
    g0 = vt + ((size_t)(b * H_ + h) * D_ + d0) * S_ + c0 * 8;
    g1 = vt + ((size_t)(b * H_ + h) * D_ + d1) * S_ + c1 * 8;
    gstep = 32;
    dst0 = d0 * 40 + c0 * 8;
    dst1 = d1 * 40 + c1 * 8;
  }

  // ds_read offsets (element units)
  const int ko0 = lj * 72 + lg * 8;            // keys lj,    d 0-31
  const int ko1 = lj * 72 + 32 + lg * 8;       // keys lj,    d 32-63
  const int kof = 16 * 72;                     // +16 keys
  const int po = lj * 40 + lg * 8;             // P read: q=lj, k=lg*8..

  // ---- prologue: stage tile tbu into buf0; prefetch tbu+1 ----
  {
    u16* kl = stK ? klds[0] : vlds[0];
    *(uint4*)(kl + dst0) = *(const uint4*)(g0 + gstep * tbu);
    *(uint4*)(kl + dst1) = *(const uint4*)(g1 + gstep * tbu);
  }
  uint4 greg0, greg1;
  if (tbu < teu) {
    greg0 = *(const uint4*)(g0 + gstep * (tbu + 1));
    greg1 = *(const uint4*)(g1 + gstep * (tbu + 1));
  }
  __syncthreads();

  int cur = 0;
  for (int t = tbu; t <= teu; ++t) {
    if (t >= tbq[0] && t <= teq[1]) {   // wave participates with >=1 qset
      const u16* K = klds[cur];
      const u16* V = vlds[cur];
      bf16x8 k00 = *(const bf16x8*)(K + ko0);
      bf16x8 k01 = *(const bf16x8*)(K + ko1);
      bf16x8 k10 = *(const bf16x8*)(K + ko0 + kof);
      bf16x8 k11 = *(const bf16x8*)(K + ko1 + kof);
      bf16x8 v0 = *(const bf16x8*)(V + (lj) * 40 + lg * 8);
      bf16x8 v1 = *(const bf16x8*)(V + (16 + lj) * 40 + lg * 8);
      bf16x8 v2 = *(const bf16x8*)(V + (32 + lj) * 40 + lg * 8);
      bf16x8 v3 = *(const bf16x8*)(V + (48 + lj) * 40 + lg * 8);

#pragma unroll
      for (int qs = 0; qs < 2; ++qs) {
        if (t < tbq[qs] || t > teq[qs]) continue;
        f32x4 sA = {0.f, 0.f, 0.f, 0.f}, sB = sA;
        sA = MFMA(aq[qs][0], k00, sA);
        sA = MFMA(aq[qs][1], k01, sA);
        sB = MFMA(aq[qs][0], k10, sB);
        sB = MFMA(aq[qs][1], k11, sB);

        const bool edge = (t == teq[qs]) || (wm[qs] && t == tbq[qs]);
        u16* ps = &plds[wave][qs][0];
#pragma unroll
        for (int r = 0; r < 4; ++r) {
          float ea = __builtin_amdgcn_exp2f(sA[r]);
          float eb = __builtin_amdgcn_exp2f(sB[r]);
          if (edge) {
            const int qpos = q0w + qs * 16 + lg * 4 + r;
            const int kA = 32 * t + lj, kB = kA + 16;
            const bool okA = (kA <= qpos) && (kA > qpos - WIN_);
            const bool okB = (kB <= qpos) && (kB > qpos - WIN_);
            ea = okA ? ea : 0.f;
            eb = okB ? eb : 0.f;
          }
          lacc[qs][r] += ea + eb;
          // truncating f32->bf16 (1 VALU each); softmax ratio cancels bias
          ps[(lg * 4 + r) * 40 + lj] = (u16)(__float_as_uint(ea) >> 16);
          ps[(lg * 4 + r) * 40 + 16 + lj] = (u16)(__float_as_uint(eb) >> 16);
        }
        bf16x8 ap = *(const bf16x8*)(ps + po);
        o[qs][0] = MFMA(ap, v0, o[qs][0]);
        o[qs][1] = MFMA(ap, v1, o[qs][1]);
        o[qs][2] = MFMA(ap, v2, o[qs][2]);
        o[qs][3] = MFMA(ap, v3, o[qs][3]);
      }
    }

    if (t < teu) {
      u16* dl = stK ? klds[cur ^ 1] : vlds[cur ^ 1];
      *(uint4*)(dl + dst0) = greg0;
      *(uint4*)(dl + dst1) = greg1;
    }
    __syncthreads();
    if (t + 1 < teu) {
      greg0 = *(const uint4*)(g0 + gstep * (t + 2));
      greg1 = *(const uint4*)(g1 + gstep * (t + 2));
    }
    cur ^= 1;
  }

  // ---- epilogue: reduce l over 16 key-columns, normalize, store bf16 ----
#pragma unroll
  for (int qs = 0; qs < 2; ++qs) {
#pragma unroll
    for (int r = 0; r < 4; ++r) {
      float l = lacc[qs][r];
      l += __shfl_xor(l, 1);
      l += __shfl_xor(l, 2);
      l += __shfl_xor(l, 4);
      l += __shfl_xor(l, 8);
      const float inv = 1.0f / l;
      const int row = q0w + qs * 16 + lg * 4 + r;
      u16* orow = attn + (size_t)(b * S_ + row) * HD_ + h * D_;
      orow[lj] = f2bf(o[qs][0][r] * inv);
      orow[16 + lj] = f2bf(o[qs][1][r] * inv);
      orow[32 + lj] = f2bf(o[qs][2][r] * inv);
      orow[48 + lj] = f2bf(o[qs][3][r] * inv);
    }
  }
}

// ---------------------------------------------------------------------------
// out = attn[16384,512](bf16) @ W^T + bias, fp32 out. (unchanged from R9)
// ---------------------------------------------------------------------------
__global__ __launch_bounds__(512) void gemm_kernel(const u16* __restrict__ A,
                                                   const u16* __restrict__ Wb,
                                                   const float* __restrict__ bias,
                                                   float* __restrict__ out) {
  const int tid = threadIdx.x;
  const int lane = tid & 63;
  const int wave = tid >> 6;
  const int lg = lane >> 4, lj = lane & 15;
  const int phys = (int)blockIdx.x;
  const int swz = (phys & 7) * 32 + (phys >> 3);
  const int rb = swz >> 1, cb = swz & 1;
  const int wr = wave >> 2, wc = wave & 3;
  const int row0 = rb * 128;
  const int col0 = cb * 256 + wc * 64;

  __shared__ __align__(16) u16 alds[2][128 * 64];

  const int srow = tid >> 3;
  const int skc = tid & 7;
  const u16* ag0 = A + (size_t)(row0 + srow) * HD_ + skc * 8;
  const u16* ag1 = A + (size_t)(row0 + 64 + srow) * HD_ + skc * 8;
  const int dst0 = srow * 64 + ((skc * 8) ^ ((srow & 7) << 3));
  const int dst1 = (64 + srow) * 64 + ((skc * 8) ^ ((srow & 7) << 3));

  f32x4 acc[4][4];
#pragma unroll
  for (int fr = 0; fr < 4; ++fr)
#pragma unroll
    for (int fc = 0; fc < 4; ++fc) acc[fr][fc] = (f32x4){0.f, 0.f, 0.f, 0.f};

  *(uint4*)(&alds[0][dst0]) = *(const uint4*)ag0;
  *(uint4*)(&alds[0][dst1]) = *(const uint4*)ag1;
  __syncthreads();

  uint4 pre0, pre1;
  int cur = 0;
  for (int kt = 0; kt < HD_; kt += 64) {
    if (kt + 64 < HD_) {
      pre0 = *(const uint4*)(ag0 + kt + 64);
      pre1 = *(const uint4*)(ag1 + kt + 64);
    }
    const u16* Abuf = alds[cur];
#pragma unroll
    for (int ks = 0; ks < 2; ++ks) {
      bf16x8 fa[4], fb[4];
#pragma unroll
      for (int fr = 0; fr < 4; ++fr) {
        const int rr = wr * 64 + fr * 16 + lj;
        fa[fr] = *(const bf16x8*)(Abuf + rr * 64 + ((ks * 32 + lg * 8) ^ ((lj & 7) << 3)));
      }
#pragma unroll
      for (int fc = 0; fc < 4; ++fc)
        fb[fc] = *(const bf16x8*)(Wb + (size_t)(col0 + fc * 16 + lj) * HD_ + kt + ks * 32 + lg * 8);
#pragma unroll
      for (int fr = 0; fr < 4; ++fr)
#pragma unroll
        for (int fc = 0; fc < 4; ++fc)
          acc[fr][fc] = MFMA(fa[fr], fb[fc], acc[fr][fc]);
    }
    if (kt + 64 < HD_) {
      u16* db = alds[cur ^ 1];
      *(uint4*)(&db[dst0]) = pre0;
      *(uint4*)(&db[dst1]) = pre1;
    }
    __syncthreads();
    cur ^= 1;
  }

#pragma unroll
  for (int fc = 0; fc < 4; ++fc) {
    const float bv = bias[col0 + fc * 16 + lj];
#pragma unroll
    for (int fr = 0; fr < 4; ++fr) {
#pragma unroll
      for (int r = 0; r < 4; ++r) {
        const int row = row0 + wr * 64 + fr * 16 + lg * 4 + r;
        out[(size_t)row * HD_ + col0 + fc * 16 + lj] = acc[fr][fc][r] + bv;
      }
    }
  }
}

// ---------------------------------------------------------------------------
extern "C" void kernel_launch(void* const* d_in, const int* in_sizes, int n_in,
                              void* d_out, int out_size, void* d_ws, size_t ws_size,
                              hipStream_t stream) {
  const float* q = (const float*)d_in[0];
  const float* k = (const float*)d_in[1];
  const float* v = (const float*)d_in[2];
  const float* w = (const float*)d_in[3];
  const float* bias = (const float*)d_in[4];
  float* out = (float*)d_out;

  char* ws = (char*)d_ws;
  u16* vt = (u16*)ws;                        // 16,777,216 B : V^T bf16 [B,H,D,S]
  u16* kbb = (u16*)(ws + 16777216);          // 16,777,216 B : K bf16 [B,S,H,D]
  u16* attn = (u16*)(ws + 33554432);         // 16,777,216 B : attn bf16 [B*S, 512]
  u16* wb = (u16*)(ws + 50331648);           //    524,288 B : W bf16 [512,512]

  hipLaunchKernelGGL(vtrans_kernel, dim3(2048), dim3(256), 0, stream, v, vt);
  hipLaunchKernelGGL(cvt_kernel, dim3(8192), dim3(256), 0, stream, k, kbb, 2097152);
  hipLaunchKernelGGL(cvt_kernel, dim3(256), dim3(256), 0, stream, w, wb, 65536);
  // attention: B*H*(S/128) = 1024 blocks x 4 waves (32 queries each)
  hipLaunchKernelGGL(attn_kernel, dim3(1024), dim3(256), 0, stream, q, kbb, vt, attn);
  // out-projection: 128 row-blocks x 2 col-blocks = 256 blocks, 512 threads
  hipLaunchKernelGGL(gemm_kernel, dim3(256), dim3(512), 0, stream, attn, wb, bias, out);
}

// Round 11
// 103.597 us; speedup vs baseline: 1.0027x; 1.0027x over previous
//
#include <hip/hip_runtime.h>

#define B_ 2
#define S_ 8192
#define H_ 8
#define D_ 64
#define HD_ 512
#define WIN_ 512

typedef __bf16 bf16x8 __attribute__((ext_vector_type(8)));
typedef float f32x4 __attribute__((ext_vector_type(4)));
typedef unsigned short u16;
typedef unsigned int u32;

__device__ __forceinline__ u16 f2bf(float f) {
  u32 u = __float_as_uint(f);
  u += 0x7FFFu + ((u >> 16) & 1u);
  return (u16)(u >> 16);
}

__device__ __forceinline__ bf16x8 cvt8s(const float* p, float s) {
  const float4 a = *(const float4*)p;
  const float4 b = *(const float4*)(p + 4);
  union { u16 s[8]; bf16x8 v; } r;
  r.s[0] = f2bf(a.x * s); r.s[1] = f2bf(a.y * s); r.s[2] = f2bf(a.z * s); r.s[3] = f2bf(a.w * s);
  r.s[4] = f2bf(b.x * s); r.s[5] = f2bf(b.y * s); r.s[6] = f2bf(b.z * s); r.s[7] = f2bf(b.w * s);
  return r.v;
}

#define MFMA(a, b, c) __builtin_amdgcn_mfma_f32_16x16x32_bf16(a, b, c, 0, 0, 0)

// ---------------------------------------------------------------------------
// V [B,S,H,D] fp32 -> Vt [B,H,D,S] bf16  (LDS-tiled transpose, 64x64 tiles)
// ---------------------------------------------------------------------------
__global__ __launch_bounds__(256) void vtrans_kernel(const float* __restrict__ v,
                                                     u16* __restrict__ vt) {
  const int t = threadIdx.x;
  const int s0 = (blockIdx.x & (S_ / 64 - 1)) * 64;
  const int bh = blockIdx.x >> 7;  // S_/64 = 128
  const int b = bh >> 3, h = bh & 7;
  __shared__ float tile[64][65];
#pragma unroll
  for (int it = 0; it < 16; ++it) {
    int idx = it * 256 + t;
    int r = idx >> 6, c = idx & 63;
    tile[r][c] = v[((size_t)(b * S_ + s0 + r) * H_ + h) * D_ + c];
  }
  __syncthreads();
#pragma unroll
  for (int it = 0; it < 16; ++it) {
    int idx = it * 256 + t;
    int dd = idx >> 6, c = idx & 63;
    vt[((size_t)(b * H_ + h) * D_ + dd) * S_ + s0 + c] = f2bf(tile[c][dd]);
  }
}

// ---------------------------------------------------------------------------
// generic fp32 -> bf16 conversion (vectorized x4)
// ---------------------------------------------------------------------------
__global__ __launch_bounds__(256) void cvt_kernel(const float* __restrict__ in,
                                                  u16* __restrict__ out, int n4) {
  int i = blockIdx.x * 256 + threadIdx.x;
  if (i < n4) {
    float4 f = ((const float4*)in)[i];
    ushort4 r;
    r.x = f2bf(f.x); r.y = f2bf(f.y); r.z = f2bf(f.z); r.w = f2bf(f.w);
    ((ushort4*)out)[i] = r;
  }
}

// ---------------------------------------------------------------------------
// Block-cooperative sliding-window flash attention (R8 structure).
// 512 threads = 8 waves x 16 queries. Block owns 128 q, shared K/V staging
// (XOR-swizzled, double-buffered, 1 barrier/tile). P-transpose LDS rows are
// 36 elem (72B) so the b16 P-writes hit all 32 banks (conflict-free).
// Fixed-reference exp2 softmax; truncating P->bf16 (1 VALU).
// ---------------------------------------------------------------------------
__global__ __launch_bounds__(512) void attn_kernel(const float* __restrict__ q,
                                                   const u16* __restrict__ kb,
                                                   const u16* __restrict__ vt,
                                                   u16* __restrict__ attn) {
  const int tid = threadIdx.x;
  const int lane = tid & 63;
  const int wave = tid >> 6;
  const int lg = lane >> 4;   // 0..3
  const int lj = lane & 15;   // 0..15
  // XCD swizzle: 1024 blocks, 8 XCDs, 128-block contiguous chunks (bijective)
  const int bid = (int)blockIdx.x;
  const int swz = (bid & 7) * 128 + (bid >> 3);
  const int qc = swz & 63;
  const int bh = swz >> 6;
  const int b = bh >> 3, h = bh & 7;
  const int q0blk = qc * 128;
  const int q0w = q0blk + wave * 16;

  __shared__ __align__(16) u16 klds0[32 * 64], klds1[32 * 64];  // 4KB each
  __shared__ __align__(16) u16 vlds0[64 * 32], vlds1[64 * 32];  // 4KB each
  __shared__ __align__(16) u16 plds[8][16 * 36];                // 1152B/wave

  const float qscale = 0.125f * 1.4426950408889634f;
  bf16x8 aq0, aq1;
  {
    const float* qrow = q + ((size_t)(b * S_ + q0w + lj) * H_ + h) * D_;
    aq0 = cvt8s(qrow + lg * 8, qscale);
    aq1 = cvt8s(qrow + 32 + lg * 8, qscale);
  }

  f32x4 o0 = {0.f, 0.f, 0.f, 0.f}, o1 = o0, o2 = o0, o3 = o0;
  float lacc[4] = {0.f, 0.f, 0.f, 0.f};

  const int tbw = (q0w >= WIN_) ? ((q0w - (WIN_ - 1)) >> 5) : 0;
  const int tew = (q0w + 15) >> 5;
  const int tbu = (q0blk >= WIN_) ? ((q0blk - (WIN_ - 1)) >> 5) : 0;
  const int teu = (q0blk + 127) >> 5;
  const bool wmask = (q0w >= WIN_);

  const bool isK = (wave < 4);
  const u16* gbase;
  size_t gstep;
  u16 *l0, *l1;
  if (isK) {
    const int chunk = wave * 64 + lane;
    const int r = chunk >> 3, c = chunk & 7;
    gbase = kb + ((size_t)(b * S_ + r) * H_ + h) * D_ + c * 8;
    gstep = (size_t)32 * HD_;
    const int dst = r * 64 + ((c * 8) ^ ((r & 7) << 3));
    l0 = klds0 + dst; l1 = klds1 + dst;
  } else {
    const int chunk = (wave - 4) * 64 + lane;
    const int d = chunk >> 2, c = chunk & 3;
    gbase = vt + ((size_t)(b * H_ + h) * D_ + d) * S_ + c * 8;
    gstep = 32;
    const int dst = d * 32 + ((c * 8) ^ ((d & 3) << 3));
    l0 = vlds0 + dst; l1 = vlds1 + dst;
  }

  const int ko0 = lj * 64 + ((lg * 8) ^ ((lj & 7) << 3));
  const int ko1 = lj * 64 + (((32 + lg * 8)) ^ ((lj & 7) << 3));
  const int vo = lj * 32 + ((lg * 8) ^ ((lj & 3) << 3));
  const int po = lj * 36 + lg * 8;   // P read: q=lj, k=lg*8..lg*8+7

  {
    uint4 g0 = *(const uint4*)(gbase + gstep * tbu);
    *(uint4*)l0 = g0;
  }
  uint4 greg;
  if (tbu < teu) greg = *(const uint4*)(gbase + gstep * (tbu + 1));
  __syncthreads();

  int cur = 0;
  for (int t = tbu; t <= teu; ++t) {
    if (t >= tbw && t <= tew) {
      const u16* K = cur ? klds1 : klds0;
      const u16* V = cur ? vlds1 : vlds0;
      bf16x8 k00 = *(const bf16x8*)(K + ko0);
      bf16x8 k01 = *(const bf16x8*)(K + ko1);
      bf16x8 k10 = *(const bf16x8*)(K + ko0 + 1024);
      bf16x8 k11 = *(const bf16x8*)(K + ko1 + 1024);

      f32x4 sA = {0.f, 0.f, 0.f, 0.f}, sB = sA;
      sA = MFMA(aq0, k00, sA);
      sA = MFMA(aq1, k01, sA);
      sB = MFMA(aq0, k10, sB);
      sB = MFMA(aq1, k11, sB);

      const bool edge = (t == tew) || (wmask && t == tbw);
      u16* ps = &plds[wave][0];
#pragma unroll
      for (int r = 0; r < 4; ++r) {
        float ea = __builtin_amdgcn_exp2f(sA[r]);
        float eb = __builtin_amdgcn_exp2f(sB[r]);
        if (edge) {
          const int qpos = q0w + lg * 4 + r;
          const int kA = 32 * t + lj, kB = kA + 16;
          const bool okA = (kA <= qpos) && (kA > qpos - WIN_);
          const bool okB = (kB <= qpos) && (kB > qpos - WIN_);
          ea = okA ? ea : 0.f;
          eb = okB ? eb : 0.f;
        }
        lacc[r] += ea + eb;
        // truncating f32->bf16 (1 VALU); softmax ratio cancels the bias
        ps[(lg * 4 + r) * 36 + lj] = (u16)(__float_as_uint(ea) >> 16);
        ps[(lg * 4 + r) * 36 + 16 + lj] = (u16)(__float_as_uint(eb) >> 16);
      }
      bf16x8 ap = *(const bf16x8*)(ps + po);

      bf16x8 v0 = *(const bf16x8*)(V + vo);
      bf16x8 v1 = *(const bf16x8*)(V + vo + 512);
      bf16x8 v2 = *(const bf16x8*)(V + vo + 1024);
      bf16x8 v3 = *(const bf16x8*)(V + vo + 1536);
      o0 = MFMA(ap, v0, o0);
      o1 = MFMA(ap, v1, o1);
      o2 = MFMA(ap, v2, o2);
      o3 = MFMA(ap, v3, o3);
    }

    if (t < teu) {
      u16* dst = cur ? l0 : l1;
      *(uint4*)dst = greg;
    }
    __syncthreads();
    if (t + 1 < teu) greg = *(const uint4*)(gbase + gstep * (t + 2));
    cur ^= 1;
  }

#pragma unroll
  for (int r = 0; r < 4; ++r) {
    float l = lacc[r];
    l += __shfl_xor(l, 1);
    l += __shfl_xor(l, 2);
    l += __shfl_xor(l, 4);
    l += __shfl_xor(l, 8);
    const float inv = 1.0f / l;
    const int row = q0w + lg * 4 + r;
    u16* orow = attn + (size_t)(b * S_ + row) * HD_ + h * D_;
    orow[lj] = f2bf(o0[r] * inv);
    orow[16 + lj] = f2bf(o1[r] * inv);
    orow[32 + lj] = f2bf(o2[r] * inv);
    orow[48 + lj] = f2bf(o3[r] * inv);
  }
}

// ---------------------------------------------------------------------------
// out = attn[16384,512](bf16) @ W^T + bias, fp32 out. (unchanged from R9)
// ---------------------------------------------------------------------------
__global__ __launch_bounds__(512) void gemm_kernel(const u16* __restrict__ A,
                                                   const u16* __restrict__ Wb,
                                                   const float* __restrict__ bias,
                                                   float* __restrict__ out) {
  const int tid = threadIdx.x;
  const int lane = tid & 63;
  const int wave = tid >> 6;
  const int lg = lane >> 4, lj = lane & 15;
  const int phys = (int)blockIdx.x;
  const int swz = (phys & 7) * 32 + (phys >> 3);
  const int rb = swz >> 1, cb = swz & 1;
  const int wr = wave >> 2, wc = wave & 3;
  const int row0 = rb * 128;
  const int col0 = cb * 256 + wc * 64;

  __shared__ __align__(16) u16 alds[2][128 * 64];

  const int srow = tid >> 3;
  const int skc = tid & 7;
  const u16* ag0 = A + (size_t)(row0 + srow) * HD_ + skc * 8;
  const u16* ag1 = A + (size_t)(row0 + 64 + srow) * HD_ + skc * 8;
  const int dst0 = srow * 64 + ((skc * 8) ^ ((srow & 7) << 3));
  const int dst1 = (64 + srow) * 64 + ((skc * 8) ^ ((srow & 7) << 3));

  f32x4 acc[4][4];
#pragma unroll
  for (int fr = 0; fr < 4; ++fr)
#pragma unroll
    for (int fc = 0; fc < 4; ++fc) acc[fr][fc] = (f32x4){0.f, 0.f, 0.f, 0.f};

  *(uint4*)(&alds[0][dst0]) = *(const uint4*)ag0;
  *(uint4*)(&alds[0][dst1]) = *(const uint4*)ag1;
  __syncthreads();

  uint4 pre0, pre1;
  int cur = 0;
  for (int kt = 0; kt < HD_; kt += 64) {
    if (kt + 64 < HD_) {
      pre0 = *(const uint4*)(ag0 + kt + 64);
      pre1 = *(const uint4*)(ag1 + kt + 64);
    }
    const u16* Abuf = alds[cur];
#pragma unroll
    for (int ks = 0; ks < 2; ++ks) {
      bf16x8 fa[4], fb[4];
#pragma unroll
      for (int fr = 0; fr < 4; ++fr) {
        const int rr = wr * 64 + fr * 16 + lj;
        fa[fr] = *(const bf16x8*)(Abuf + rr * 64 + ((ks * 32 + lg * 8) ^ ((lj & 7) << 3)));
      }
#pragma unroll
      for (int fc = 0; fc < 4; ++fc)
        fb[fc] = *(const bf16x8*)(Wb + (size_t)(col0 + fc * 16 + lj) * HD_ + kt + ks * 32 + lg * 8);
#pragma unroll
      for (int fr = 0; fr < 4; ++fr)
#pragma unroll
        for (int fc = 0; fc < 4; ++fc)
          acc[fr][fc] = MFMA(fa[fr], fb[fc], acc[fr][fc]);
    }
    if (kt + 64 < HD_) {
      u16* db = alds[cur ^ 1];
      *(uint4*)(&db[dst0]) = pre0;
      *(uint4*)(&db[dst1]) = pre1;
    }
    __syncthreads();
    cur ^= 1;
  }

#pragma unroll
  for (int fc = 0; fc < 4; ++fc) {
    const float bv = bias[col0 + fc * 16 + lj];
#pragma unroll
    for (int fr = 0; fr < 4; ++fr) {
#pragma unroll
      for (int r = 0; r < 4; ++r) {
        const int row = row0 + wr * 64 + fr * 16 + lg * 4 + r;
        out[(size_t)row * HD_ + col0 + fc * 16 + lj] = acc[fr][fc][r] + bv;
      }
    }
  }
}

// ---------------------------------------------------------------------------
extern "C" void kernel_launch(void* const* d_in, const int* in_sizes, int n_in,
                              void* d_out, int out_size, void* d_ws, size_t ws_size,
                              hipStream_t stream) {
  const float* q = (const float*)d_in[0];
  const float* k = (const float*)d_in[1];
  const float* v = (const float*)d_in[2];
  const float* w = (const float*)d_in[3];
  const float* bias = (const float*)d_in[4];
  float* out = (float*)d_out;

  char* ws = (char*)d_ws;
  u16* vt = (u16*)ws;                        // 16,777,216 B : V^T bf16 [B,H,D,S]
  u16* kbb = (u16*)(ws + 16777216);          // 16,777,216 B : K bf16 [B,S,H,D]
  u16* attn = (u16*)(ws + 33554432);         // 16,777,216 B : attn bf16 [B*S, 512]
  u16* wb = (u16*)(ws + 50331648);           //    524,288 B : W bf16 [512,512]

  hipLaunchKernelGGL(vtrans_kernel, dim3(2048), dim3(256), 0, stream, v, vt);
  hipLaunchKernelGGL(cvt_kernel, dim3(8192), dim3(256), 0, stream, k, kbb, 2097152);
  hipLaunchKernelGGL(cvt_kernel, dim3(256), dim3(256), 0, stream, w, wb, 65536);
  // attention: B*H*(S/128) = 1024 blocks x 8 waves (16 queries each, shared K/V)
  hipLaunchKernelGGL(attn_kernel, dim3(1024), dim3(512), 0, stream, q, kbb, vt, attn);
  // out-projection: 128 row-blocks x 2 col-blocks = 256 blocks, 512 threads
  hipLaunchKernelGGL(gemm_kernel, dim3(256), dim3(512), 0, stream, attn, wb, bias, out);
}

// Round 12
// 85.533 us; speedup vs baseline: 1.2145x; 1.2112x over previous
//
#include <hip/hip_runtime.h>

#define B_ 2
#define S_ 8192
#define H_ 8
#define D_ 64
#define HD_ 512
#define WIN_ 512

typedef __bf16 bf16x8 __attribute__((ext_vector_type(8)));
typedef float f32x4 __attribute__((ext_vector_type(4)));
typedef unsigned short u16;
typedef unsigned int u32;

__device__ __forceinline__ u16 f2bf(float f) {
  u32 u = __float_as_uint(f);
  u += 0x7FFFu + ((u >> 16) & 1u);
  return (u16)(u >> 16);
}

__device__ __forceinline__ bf16x8 cvt8s(const float* p, float s) {
  const float4 a = *(const float4*)p;
  const float4 b = *(const float4*)(p + 4);
  union { u16 s[8]; bf16x8 v; } r;
  r.s[0] = f2bf(a.x * s); r.s[1] = f2bf(a.y * s); r.s[2] = f2bf(a.z * s); r.s[3] = f2bf(a.w * s);
  r.s[4] = f2bf(b.x * s); r.s[5] = f2bf(b.y * s); r.s[6] = f2bf(b.z * s); r.s[7] = f2bf(b.w * s);
  return r.v;
}

#define MFMA(a, b, c) __builtin_amdgcn_mfma_f32_16x16x32_bf16(a, b, c, 0, 0, 0)

// ---------------------------------------------------------------------------
// generic fp32 -> bf16 conversion (vectorized x4) — used only for W now
// ---------------------------------------------------------------------------
__global__ __launch_bounds__(256) void cvt_kernel(const float* __restrict__ in,
                                                  u16* __restrict__ out, int n4) {
  int i = blockIdx.x * 256 + threadIdx.x;
  if (i < n4) {
    float4 f = ((const float4*)in)[i];
    ushort4 r;
    r.x = f2bf(f.x); r.y = f2bf(f.y); r.z = f2bf(f.z); r.w = f2bf(f.w);
    ((ushort4*)out)[i] = r;
  }
}

// ---------------------------------------------------------------------------
// Block-cooperative sliding-window flash attention (R9 structure) with FUSED
// fp32->bf16 conversion/transpose in the staging path (no pre-passes).
// 512 threads = 8 waves x 16 queries; block owns 128 q. Waves 0-3 stage K
// (fp32 read -> cvt -> b128 swizzled write), waves 4-7 stage V with on-the-fly
// transpose (fp32 row read -> 8 scattered b16 writes, 4-way by construction).
// Double-buffered, 1 barrier/tile. P rows 40 elem (16B-aligned b128 reads,
// 4-way b16 writes). Fixed-reference exp2 softmax; truncating P->bf16.
// ---------------------------------------------------------------------------
__global__ __launch_bounds__(512) void attn_kernel(const float* __restrict__ q,
                                                   const float* __restrict__ kf,
                                                   const float* __restrict__ vf,
                                                   u16* __restrict__ attn) {
  const int tid = threadIdx.x;
  const int lane = tid & 63;
  const int wave = tid >> 6;
  const int lg = lane >> 4;   // 0..3
  const int lj = lane & 15;   // 0..15
  // XCD swizzle: 1024 blocks, 8 XCDs, 128-block contiguous chunks (bijective)
  const int bid = (int)blockIdx.x;
  const int swz = (bid & 7) * 128 + (bid >> 3);
  const int qc = swz & 63;
  const int bh = swz >> 6;
  const int b = bh >> 3, h = bh & 7;
  const int q0blk = qc * 128;
  const int q0w = q0blk + wave * 16;

  __shared__ __align__(16) u16 klds0[32 * 64], klds1[32 * 64];  // 4KB each
  __shared__ __align__(16) u16 vlds0[64 * 32], vlds1[64 * 32];  // 4KB each
  __shared__ __align__(16) u16 plds[8][16 * 40];                // 1280B/wave

  const float qscale = 0.125f * 1.4426950408889634f;
  bf16x8 aq0, aq1;
  {
    const float* qrow = q + ((size_t)(b * S_ + q0w + lj) * H_ + h) * D_;
    aq0 = cvt8s(qrow + lg * 8, qscale);
    aq1 = cvt8s(qrow + 32 + lg * 8, qscale);
  }

  f32x4 o0 = {0.f, 0.f, 0.f, 0.f}, o1 = o0, o2 = o0, o3 = o0;
  float lacc[4] = {0.f, 0.f, 0.f, 0.f};

  const int tbw = (q0w >= WIN_) ? ((q0w - (WIN_ - 1)) >> 5) : 0;
  const int tew = (q0w + 15) >> 5;
  const int tbu = (q0blk >= WIN_) ? ((q0blk - (WIN_ - 1)) >> 5) : 0;
  const int teu = (q0blk + 127) >> 5;
  const bool wmask = (q0w >= WIN_);

  // ---- staging roles ----
  const bool isK = (wave < 4);
  const float* gf;           // fp32 source (within-tile offset folded in)
  const size_t gstepf = (size_t)32 * H_ * D_;  // fp32 elems per key-tile
  u16 *l0, *l1;              // K b128 dst (both buffers)
  int vkey = 0, vd0 = 0;
  if (isK) {
    const int chunk = wave * 64 + lane;        // 0..255
    const int r = chunk >> 3, c = chunk & 7;   // key row r, 8-elem d-chunk c
    gf = kf + ((size_t)(b * S_ + r) * H_ + h) * D_ + c * 8;
    const int dst = r * 64 + ((c * 8) ^ ((r & 7) << 3));
    l0 = klds0 + dst; l1 = klds1 + dst;
  } else {
    const int u = (wave - 4) * 64 + lane;      // 0..255
    vkey = u & 31;                             // key within tile
    vd0 = (u >> 5) * 8;                        // 8-d chunk
    gf = vf + ((size_t)(b * S_ + vkey) * H_ + h) * D_ + vd0;
    l0 = vlds0; l1 = vlds1;
  }

  // K b128 write from 8 fp32
  auto kpack = [](float4 a, float4 c) {
    union { u16 s[8]; uint4 q; } t;
    t.s[0] = f2bf(a.x); t.s[1] = f2bf(a.y); t.s[2] = f2bf(a.z); t.s[3] = f2bf(a.w);
    t.s[4] = f2bf(c.x); t.s[5] = f2bf(c.y); t.s[6] = f2bf(c.z); t.s[7] = f2bf(c.w);
    return t.q;
  };
  // V transpose scatter: elem (vd0+i, vkey) -> row-major-by-d swizzled LDS
  auto vscatter = [&](u16* vb, float4 a, float4 c) {
    float vals[8] = {a.x, a.y, a.z, a.w, c.x, c.y, c.z, c.w};
#pragma unroll
    for (int i = 0; i < 8; ++i) {
      const int d = vd0 + i;
      vb[d * 32 + (vkey ^ ((d & 3) << 3))] = f2bf(vals[i]);
    }
  };

  // ds_read offsets (element units)
  const int ko0 = lj * 64 + ((lg * 8) ^ ((lj & 7) << 3));
  const int ko1 = lj * 64 + (((32 + lg * 8)) ^ ((lj & 7) << 3));
  const int vo = lj * 32 + ((lg * 8) ^ ((lj & 3) << 3));
  const int po = lj * 40 + lg * 8;   // 80B rows: 16B-aligned b128 reads

  // ---- prologue: stage tile tbu into buf0; prefetch tile tbu+1 ----
  {
    float4 a = *(const float4*)(gf + gstepf * tbu);
    float4 c = *(const float4*)(gf + gstepf * tbu + 4);
    if (isK) *(uint4*)l0 = kpack(a, c);
    else vscatter(vlds0, a, c);
  }
  float4 ga, gb;
  if (tbu < teu) {
    ga = *(const float4*)(gf + gstepf * (tbu + 1));
    gb = *(const float4*)(gf + gstepf * (tbu + 1) + 4);
  }
  __syncthreads();

  int cur = 0;
  for (int t = tbu; t <= teu; ++t) {
    if (t >= tbw && t <= tew) {
      const u16* K = cur ? klds1 : klds0;
      const u16* V = cur ? vlds1 : vlds0;
      bf16x8 k00 = *(const bf16x8*)(K + ko0);
      bf16x8 k01 = *(const bf16x8*)(K + ko1);
      bf16x8 k10 = *(const bf16x8*)(K + ko0 + 1024);
      bf16x8 k11 = *(const bf16x8*)(K + ko1 + 1024);

      f32x4 sA = {0.f, 0.f, 0.f, 0.f}, sB = sA;
      sA = MFMA(aq0, k00, sA);
      sA = MFMA(aq1, k01, sA);
      sB = MFMA(aq0, k10, sB);
      sB = MFMA(aq1, k11, sB);

      const bool edge = (t == tew) || (wmask && t == tbw);
      u16* ps = &plds[wave][0];
#pragma unroll
      for (int r = 0; r < 4; ++r) {
        float ea = __builtin_amdgcn_exp2f(sA[r]);
        float eb = __builtin_amdgcn_exp2f(sB[r]);
        if (edge) {
          const int qpos = q0w + lg * 4 + r;
          const int kA = 32 * t + lj, kB = kA + 16;
          const bool okA = (kA <= qpos) && (kA > qpos - WIN_);
          const bool okB = (kB <= qpos) && (kB > qpos - WIN_);
          ea = okA ? ea : 0.f;
          eb = okB ? eb : 0.f;
        }
        lacc[r] += ea + eb;
        // truncating f32->bf16 (1 VALU); softmax ratio cancels the bias
        ps[(lg * 4 + r) * 40 + lj] = (u16)(__float_as_uint(ea) >> 16);
        ps[(lg * 4 + r) * 40 + 16 + lj] = (u16)(__float_as_uint(eb) >> 16);
      }
      bf16x8 ap = *(const bf16x8*)(ps + po);

      bf16x8 v0 = *(const bf16x8*)(V + vo);
      bf16x8 v1 = *(const bf16x8*)(V + vo + 512);
      bf16x8 v2 = *(const bf16x8*)(V + vo + 1024);
      bf16x8 v3 = *(const bf16x8*)(V + vo + 1536);
      o0 = MFMA(ap, v0, o0);
      o1 = MFMA(ap, v1, o1);
      o2 = MFMA(ap, v2, o2);
      o3 = MFMA(ap, v3, o3);
    }

    // write prefetched (converted) data into the other buffer
    if (t < teu) {
      if (isK) {
        u16* dst = cur ? l0 : l1;
        *(uint4*)dst = kpack(ga, gb);
      } else {
        vscatter(cur ? vlds0 : vlds1, ga, gb);
      }
    }
    __syncthreads();
    if (t + 1 < teu) {
      ga = *(const float4*)(gf + gstepf * (t + 2));
      gb = *(const float4*)(gf + gstepf * (t + 2) + 4);
    }
    cur ^= 1;
  }

  // ---- epilogue: reduce l over 16 key-columns, normalize, store bf16 ----
#pragma unroll
  for (int r = 0; r < 4; ++r) {
    float l = lacc[r];
    l += __shfl_xor(l, 1);
    l += __shfl_xor(l, 2);
    l += __shfl_xor(l, 4);
    l += __shfl_xor(l, 8);
    const float inv = 1.0f / l;
    const int row = q0w + lg * 4 + r;
    u16* orow = attn + (size_t)(b * S_ + row) * HD_ + h * D_;
    orow[lj] = f2bf(o0[r] * inv);
    orow[16 + lj] = f2bf(o1[r] * inv);
    orow[32 + lj] = f2bf(o2[r] * inv);
    orow[48 + lj] = f2bf(o3[r] * inv);
  }
}

// ---------------------------------------------------------------------------
// out = attn[16384,512](bf16) @ W^T + bias, fp32 out. (unchanged)
// ---------------------------------------------------------------------------
__global__ __launch_bounds__(512) void gemm_kernel(const u16* __restrict__ A,
                                                   const u16* __restrict__ Wb,
                                                   const float* __restrict__ bias,
                                                   float* __restrict__ out) {
  const int tid = threadIdx.x;
  const int lane = tid & 63;
  const int wave = tid >> 6;
  const int lg = lane >> 4, lj = lane & 15;
  const int phys = (int)blockIdx.x;
  const int swz = (phys & 7) * 32 + (phys >> 3);
  const int rb = swz >> 1, cb = swz & 1;
  const int wr = wave >> 2, wc = wave & 3;
  const int row0 = rb * 128;
  const int col0 = cb * 256 + wc * 64;

  __shared__ __align__(16) u16 alds[2][128 * 64];

  const int srow = tid >> 3;
  const int skc = tid & 7;
  const u16* ag0 = A + (size_t)(row0 + srow) * HD_ + skc * 8;
  const u16* ag1 = A + (size_t)(row0 + 64 + srow) * HD_ + skc * 8;
  const int dst0 = srow * 64 + ((skc * 8) ^ ((srow & 7) << 3));
  const int dst1 = (64 + srow) * 64 + ((skc * 8) ^ ((srow & 7) << 3));

  f32x4 acc[4][4];
#pragma unroll
  for (int fr = 0; fr < 4; ++fr)
#pragma unroll
    for (int fc = 0; fc < 4; ++fc) acc[fr][fc] = (f32x4){0.f, 0.f, 0.f, 0.f};

  *(uint4*)(&alds[0][dst0]) = *(const uint4*)ag0;
  *(uint4*)(&alds[0][dst1]) = *(const uint4*)ag1;
  __syncthreads();

  uint4 pre0, pre1;
  int cur = 0;
  for (int kt = 0; kt < HD_; kt += 64) {
    if (kt + 64 < HD_) {
      pre0 = *(const uint4*)(ag0 + kt + 64);
      pre1 = *(const uint4*)(ag1 + kt + 64);
    }
    const u16* Abuf = alds[cur];
#pragma unroll
    for (int ks = 0; ks < 2; ++ks) {
      bf16x8 fa[4], fb[4];
#pragma unroll
      for (int fr = 0; fr < 4; ++fr) {
        const int rr = wr * 64 + fr * 16 + lj;
        fa[fr] = *(const bf16x8*)(Abuf + rr * 64 + ((ks * 32 + lg * 8) ^ ((lj & 7) << 3)));
      }
#pragma unroll
      for (int fc = 0; fc < 4; ++fc)
        fb[fc] = *(const bf16x8*)(Wb + (size_t)(col0 + fc * 16 + lj) * HD_ + kt + ks * 32 + lg * 8);
#pragma unroll
      for (int fr = 0; fr < 4; ++fr)
#pragma unroll
        for (int fc = 0; fc < 4; ++fc)
          acc[fr][fc] = MFMA(fa[fr], fb[fc], acc[fr][fc]);
    }
    if (kt + 64 < HD_) {
      u16* db = alds[cur ^ 1];
      *(uint4*)(&db[dst0]) = pre0;
      *(uint4*)(&db[dst1]) = pre1;
    }
    __syncthreads();
    cur ^= 1;
  }

#pragma unroll
  for (int fc = 0; fc < 4; ++fc) {
    const float bv = bias[col0 + fc * 16 + lj];
#pragma unroll
    for (int fr = 0; fr < 4; ++fr) {
#pragma unroll
      for (int r = 0; r < 4; ++r) {
        const int row = row0 + wr * 64 + fr * 16 + lg * 4 + r;
        out[(size_t)row * HD_ + col0 + fc * 16 + lj] = acc[fr][fc][r] + bv;
      }
    }
  }
}

// ---------------------------------------------------------------------------
extern "C" void kernel_launch(void* const* d_in, const int* in_sizes, int n_in,
                              void* d_out, int out_size, void* d_ws, size_t ws_size,
                              hipStream_t stream) {
  const float* q = (const float*)d_in[0];
  const float* k = (const float*)d_in[1];
  const float* v = (const float*)d_in[2];
  const float* w = (const float*)d_in[3];
  const float* bias = (const float*)d_in[4];
  float* out = (float*)d_out;

  char* ws = (char*)d_ws;
  u16* attn = (u16*)ws;                      // 16,777,216 B : attn bf16 [B*S, 512]
  u16* wb = (u16*)(ws + 16777216);           //    524,288 B : W bf16 [512,512]

  // W convert: 262,144 / 4 = 65,536 threads
  hipLaunchKernelGGL(cvt_kernel, dim3(256), dim3(256), 0, stream, w, wb, 65536);
  // fused attention (fp32 K/V staged+converted in-kernel): 1024 blocks x 512
  hipLaunchKernelGGL(attn_kernel, dim3(1024), dim3(512), 0, stream, q, k, v, attn);
  // out-projection: 128 row-blocks x 2 col-blocks = 256 blocks, 512 threads
  hipLaunchKernelGGL(gemm_kernel, dim3(256), dim3(512), 0, stream, attn, wb, bias, out);
}